// Round 1
// baseline (224.926 us; speedup 1.0000x reference)
//
#include <hip/hip_runtime.h>

#define B_DIM 8
#define N_DIM 2048
#define F_DIM 128

typedef __attribute__((ext_vector_type(8))) __bf16 bf16x8;
typedef __attribute__((ext_vector_type(4))) float f32x4;

__device__ __forceinline__ __bf16 f2bf(float f) {
  unsigned u = __builtin_bit_cast(unsigned, f);
  u += 0x7FFFu + ((u >> 16) & 1u);                 // round-to-nearest-even
  unsigned short s = (unsigned short)(u >> 16);
  return __builtin_bit_cast(__bf16, s);
}

// Kernel 1: supT[b][j][i] = bf16( sum_f x[b][i][f] * W[f][j] )   (transposed!)
// Computed as D = W^T (A, M=j,K=f) x x^T (B, K=f,N=i) so D's col=lane&15 is the
// node index i -> contiguous stores, and so kernel 2's B-operand is k-contiguous.
__global__ __launch_bounds__(256) void gcn_xw(const float* __restrict__ x,
                                              const float* __restrict__ W,
                                              __bf16* __restrict__ supT) {
  __shared__ __bf16 WT[128 * 136];   // [j][f], stride 136 (pad 8) -> 2-way banks
  const int tid = threadIdx.x;
  const int lane = tid & 63;
  const int wave = tid >> 6;
  const int b = blockIdx.x >> 5;
  const int i0 = (blockIdx.x & 31) << 6;   // 64 nodes per WG

  // stage W transposed into LDS as bf16
  for (int p = 0; p < 8; ++p) {
    int f = p * 16 + (tid >> 4);
    int j0 = (tid & 15) << 3;
    const float4* wp = reinterpret_cast<const float4*>(W + f * 128 + j0);
    float4 w0 = wp[0];
    float4 w1 = wp[1];
    WT[(j0 + 0) * 136 + f] = f2bf(w0.x);
    WT[(j0 + 1) * 136 + f] = f2bf(w0.y);
    WT[(j0 + 2) * 136 + f] = f2bf(w0.z);
    WT[(j0 + 3) * 136 + f] = f2bf(w0.w);
    WT[(j0 + 4) * 136 + f] = f2bf(w1.x);
    WT[(j0 + 5) * 136 + f] = f2bf(w1.y);
    WT[(j0 + 6) * 136 + f] = f2bf(w1.z);
    WT[(j0 + 7) * 136 + f] = f2bf(w1.w);
  }
  __syncthreads();

  const int jt0 = wave << 1;           // each wave: 2 j-tiles x 4 i-tiles
  const int q8 = (lane >> 4) << 3;     // k offset of this quad
  const int c = lane & 15;
  f32x4 acc[2][4] = {};
  const float* xb = x + ((size_t)b * N_DIM + i0) * F_DIM;

  for (int k0 = 0; k0 < 128; k0 += 32) {
    const int kq = k0 + q8;
    bf16x8 af[2], bfr[4];
#pragma unroll
    for (int jt = 0; jt < 2; ++jt)
      af[jt] = *reinterpret_cast<const bf16x8*>(&WT[((jt0 + jt) * 16 + c) * 136 + kq]);
#pragma unroll
    for (int nt = 0; nt < 4; ++nt) {
      const float* xp = xb + (size_t)(nt * 16 + c) * F_DIM + kq;
      float4 x0 = *reinterpret_cast<const float4*>(xp);
      float4 x1 = *reinterpret_cast<const float4*>(xp + 4);
      bf16x8 v;
      v[0] = f2bf(x0.x); v[1] = f2bf(x0.y); v[2] = f2bf(x0.z); v[3] = f2bf(x0.w);
      v[4] = f2bf(x1.x); v[5] = f2bf(x1.y); v[6] = f2bf(x1.z); v[7] = f2bf(x1.w);
      bfr[nt] = v;
    }
#pragma unroll
    for (int jt = 0; jt < 2; ++jt)
#pragma unroll
      for (int nt = 0; nt < 4; ++nt)
        acc[jt][nt] = __builtin_amdgcn_mfma_f32_16x16x32_bf16(af[jt], bfr[nt],
                                                              acc[jt][nt], 0, 0, 0);
  }

  __bf16* sb = supT + (size_t)b * F_DIM * N_DIM;
  const int q = lane >> 4;
#pragma unroll
  for (int jt = 0; jt < 2; ++jt)
#pragma unroll
    for (int nt = 0; nt < 4; ++nt)
#pragma unroll
      for (int r = 0; r < 4; ++r) {
        int j = (jt0 + jt) * 16 + q * 4 + r;   // D row = quad*4 + reg
        int i = i0 + nt * 16 + c;              // D col = lane&15
        sb[(size_t)j * N_DIM + i] = f2bf(acc[jt][nt][r]);
      }
}

// Kernel 2: out[b][m][j] = sum_k adj[b][m][k] * supT[b][j][k] + bias[j]
// WG: 64(M) x 128(N) tile, BK=64, double-buffered LDS w/ register prefetch.
__global__ __launch_bounds__(256) void gcn_adj(const float* __restrict__ adj,
                                               const __bf16* __restrict__ supT,
                                               const float* __restrict__ bias,
                                               float* __restrict__ out) {
  __shared__ __bf16 As[2][64 * 72];    // adj tile [m][k], stride 72
  __shared__ __bf16 Bs[2][128 * 72];   // supT tile [n][k], stride 72
  const int tid = threadIdx.x;
  const int lane = tid & 63;
  const int wave = tid >> 6;
  const int b = blockIdx.x >> 5;
  const int m0 = (blockIdx.x & 31) << 6;

  const int msub = (wave & 1) << 5;    // wave: 32(M) x 64(N) quadrant
  const int nsub = (wave >> 1) << 6;

  const float* adjb = adj + ((size_t)b * N_DIM + m0) * N_DIM;
  const __bf16* sb = supT + (size_t)b * F_DIM * N_DIM;

  const int arow = tid >> 2;           // adj staging: 4 thr/row, 16 f32 each
  const int acol = (tid & 3) << 4;
  const int srow = tid >> 3;           // sup staging: 8 thr/row, 8 bf16 each
  const int scol = (tid & 7) << 3;

  float4 pa[4];
  bf16x8 ps[4];

  auto load_tile = [&](int kk) {
    const float4* ap = reinterpret_cast<const float4*>(adjb + (size_t)arow * N_DIM + kk + acol);
    pa[0] = ap[0]; pa[1] = ap[1]; pa[2] = ap[2]; pa[3] = ap[3];
#pragma unroll
    for (int p = 0; p < 4; ++p)
      ps[p] = *reinterpret_cast<const bf16x8*>(sb + (size_t)(srow + p * 32) * N_DIM + kk + scol);
  };
  auto store_tile = [&](int buf) {
    bf16x8 v0, v1;
    v0[0] = f2bf(pa[0].x); v0[1] = f2bf(pa[0].y); v0[2] = f2bf(pa[0].z); v0[3] = f2bf(pa[0].w);
    v0[4] = f2bf(pa[1].x); v0[5] = f2bf(pa[1].y); v0[6] = f2bf(pa[1].z); v0[7] = f2bf(pa[1].w);
    v1[0] = f2bf(pa[2].x); v1[1] = f2bf(pa[2].y); v1[2] = f2bf(pa[2].z); v1[3] = f2bf(pa[2].w);
    v1[4] = f2bf(pa[3].x); v1[5] = f2bf(pa[3].y); v1[6] = f2bf(pa[3].z); v1[7] = f2bf(pa[3].w);
    *reinterpret_cast<bf16x8*>(&As[buf][arow * 72 + acol]) = v0;
    *reinterpret_cast<bf16x8*>(&As[buf][arow * 72 + acol + 8]) = v1;
#pragma unroll
    for (int p = 0; p < 4; ++p)
      *reinterpret_cast<bf16x8*>(&Bs[buf][(srow + p * 32) * 72 + scol]) = ps[p];
  };

  f32x4 acc[2][4] = {};
  const int q8 = (lane >> 4) << 3;
  const int c = lane & 15;

  load_tile(0);
  store_tile(0);
  __syncthreads();

  for (int it = 1; it <= 32; ++it) {
    const int cur = (it - 1) & 1;
    const int nxt = it & 1;
    if (it < 32) load_tile(it * 64);   // global loads in flight over compute
#pragma unroll
    for (int k2 = 0; k2 < 2; ++k2) {
      const int kb = k2 * 32 + q8;
      bf16x8 af[2], bfr[4];
#pragma unroll
      for (int mt = 0; mt < 2; ++mt)
        af[mt] = *reinterpret_cast<const bf16x8*>(&As[cur][(msub + mt * 16 + c) * 72 + kb]);
#pragma unroll
      for (int nt = 0; nt < 4; ++nt)
        bfr[nt] = *reinterpret_cast<const bf16x8*>(&Bs[cur][(nsub + nt * 16 + c) * 72 + kb]);
#pragma unroll
      for (int mt = 0; mt < 2; ++mt)
#pragma unroll
        for (int nt = 0; nt < 4; ++nt)
          acc[mt][nt] = __builtin_amdgcn_mfma_f32_16x16x32_bf16(af[mt], bfr[nt],
                                                                acc[mt][nt], 0, 0, 0);
    }
    if (it < 32) store_tile(nxt);
    __syncthreads();
  }

  const int q = lane >> 4;
  float bv[4];
#pragma unroll
  for (int nt = 0; nt < 4; ++nt) bv[nt] = bias[nsub + nt * 16 + c];
#pragma unroll
  for (int mt = 0; mt < 2; ++mt)
#pragma unroll
    for (int nt = 0; nt < 4; ++nt)
#pragma unroll
      for (int r = 0; r < 4; ++r) {
        int m = m0 + msub + mt * 16 + q * 4 + r;
        int j = nsub + nt * 16 + c;
        out[((size_t)b * N_DIM + m) * F_DIM + j] = acc[mt][nt][r] + bv[nt];
      }
}

extern "C" void kernel_launch(void* const* d_in, const int* in_sizes, int n_in,
                              void* d_out, int out_size, void* d_ws, size_t ws_size,
                              hipStream_t stream) {
  const float* x    = (const float*)d_in[0];
  const float* adj  = (const float*)d_in[1];
  const float* W    = (const float*)d_in[2];
  const float* bias = (const float*)d_in[3];
  float* out = (float*)d_out;
  __bf16* supT = (__bf16*)d_ws;   // 8*128*2048*2 = 4 MB scratch

  gcn_xw<<<B_DIM * 32, 256, 0, stream>>>(x, W, supT);
  gcn_adj<<<B_DIM * 32, 256, 0, stream>>>(adj, supT, bias, out);
}

// Round 3
// 220.310 us; speedup vs baseline: 1.0210x; 1.0210x over previous
//
#include <hip/hip_runtime.h>

#define B_DIM 8
#define N_DIM 2048
#define F_DIM 128

typedef __attribute__((ext_vector_type(8))) __bf16 bf16x8;
typedef __attribute__((ext_vector_type(4))) float f32x4;

__device__ __forceinline__ __bf16 f2bf(float f) {
  unsigned u = __builtin_bit_cast(unsigned, f);
  u += 0x7FFFu + ((u >> 16) & 1u);                 // round-to-nearest-even
  unsigned short s = (unsigned short)(u >> 16);
  return __builtin_bit_cast(__bf16, s);
}

// Kernel 1: supT[b][j][i] = bf16( sum_f x[b][i][f] * W[f][j] )   (transposed!)
// D = W^T (A: M=j,K=f) x x^T (B: K=f,N=i); D col=lane&15 = node i -> contiguous
// stores, and kernel 2's B-operand becomes k-contiguous.
__global__ __launch_bounds__(256) void gcn_xw(const float* __restrict__ x,
                                              const float* __restrict__ W,
                                              __bf16* __restrict__ supT) {
  __shared__ __bf16 WT[128 * 136];   // [j][f], stride 136 -> 2-way banks on read
  const int tid = threadIdx.x;
  const int lane = tid & 63;
  const int wave = tid >> 6;
  const int b = blockIdx.x >> 5;
  const int i0 = (blockIdx.x & 31) << 6;   // 64 nodes per WG

  // Stage W^T into LDS: thread owns column j, 8 f-octs of 8. Global reads are
  // lane-coalesced (lane j -> consecutive 4B); one ds_write_b128 per oct.
  {
    const int j = tid & 127;
    const int fh = (tid >> 7) << 6;          // 0 or 64
#pragma unroll
    for (int p = 0; p < 8; ++p) {
      const int f0 = fh + p * 8;
      bf16x8 v;
#pragma unroll
      for (int e = 0; e < 8; ++e)
        v[e] = f2bf(W[(size_t)(f0 + e) * 128 + j]);
      *reinterpret_cast<bf16x8*>(&WT[j * 136 + f0]) = v;
    }
  }
  __syncthreads();

  const int jt0 = wave << 1;           // each wave: 2 j-tiles x 4 i-tiles
  const int q8 = (lane >> 4) << 3;     // k offset of this quad
  const int c = lane & 15;
  f32x4 acc[2][4] = {};
  const float* xb = x + ((size_t)b * N_DIM + i0) * F_DIM;

  for (int k0 = 0; k0 < 128; k0 += 32) {
    const int kq = k0 + q8;
    bf16x8 af[2], bfr[4];
#pragma unroll
    for (int jt = 0; jt < 2; ++jt)
      af[jt] = *reinterpret_cast<const bf16x8*>(&WT[((jt0 + jt) * 16 + c) * 136 + kq]);
#pragma unroll
    for (int nt = 0; nt < 4; ++nt) {
      const float* xp = xb + (size_t)(nt * 16 + c) * F_DIM + kq;
      f32x4 x0 = *reinterpret_cast<const f32x4*>(xp);
      f32x4 x1 = *reinterpret_cast<const f32x4*>(xp + 4);
      bf16x8 v;
      v[0] = f2bf(x0.x); v[1] = f2bf(x0.y); v[2] = f2bf(x0.z); v[3] = f2bf(x0.w);
      v[4] = f2bf(x1.x); v[5] = f2bf(x1.y); v[6] = f2bf(x1.z); v[7] = f2bf(x1.w);
      bfr[nt] = v;
    }
#pragma unroll
    for (int jt = 0; jt < 2; ++jt)
#pragma unroll
      for (int nt = 0; nt < 4; ++nt)
        acc[jt][nt] = __builtin_amdgcn_mfma_f32_16x16x32_bf16(af[jt], bfr[nt],
                                                              acc[jt][nt], 0, 0, 0);
  }

  __bf16* sb = supT + (size_t)b * F_DIM * N_DIM;
  const int q = lane >> 4;
#pragma unroll
  for (int jt = 0; jt < 2; ++jt)
#pragma unroll
    for (int nt = 0; nt < 4; ++nt)
#pragma unroll
      for (int r = 0; r < 4; ++r) {
        int j = (jt0 + jt) * 16 + q * 4 + r;   // D row = quad*4 + reg
        int i = i0 + nt * 16 + c;              // D col = lane&15
        sb[(size_t)j * N_DIM + i] = f2bf(acc[jt][nt][r]);
      }
}

// Kernel 2: out[b][m][j] = sum_k adj[b][m][k] * supT[b][j][k] + bias[j]
// 32(M) x 128(N) tile per 256-thr WG; grid 512 = 2 blocks/CU, 8 waves/CU so
// one block computes while the other drains its barrier. b = blockIdx&7 pins
// each batch to one XCD (round-robin dispatch) -> supT[b] stays in that L2;
// adj reads are nontemporal so the stream doesn't evict it.
__global__ __launch_bounds__(256, 2) void gcn_adj(const float* __restrict__ adj,
                                                  const __bf16* __restrict__ supT,
                                                  const float* __restrict__ bias,
                                                  float* __restrict__ out) {
  __shared__ __bf16 As[2][32 * 72];    // adj tile [m][k] bf16, stride 72
  __shared__ __bf16 Bs[2][128 * 72];   // supT tile [n][k], stride 72
  const int tid = threadIdx.x;
  const int lane = tid & 63;
  const int wave = tid >> 6;
  const int b = blockIdx.x & 7;
  const int m0 = (blockIdx.x >> 3) << 5;

  const int nsub = wave << 5;          // each wave: full 32(M) x 32(N)

  const float* adjb = adj + ((size_t)b * N_DIM + m0) * N_DIM;
  const __bf16* sb = supT + (size_t)b * F_DIM * N_DIM;

  const int arow = tid >> 3;           // adj staging: 8 thr/row, 8 f32 each
  const int acol = (tid & 7) << 3;
  const int srow = tid >> 3;           // sup staging: 8 thr/row, 8 bf16, 4 passes
  const int scol = (tid & 7) << 3;

  f32x4 pa[2];
  bf16x8 ps[4];

  auto load_tile = [&](int kk) {
    const f32x4* ap = reinterpret_cast<const f32x4*>(adjb + (size_t)arow * N_DIM + kk + acol);
    pa[0] = __builtin_nontemporal_load(ap);
    pa[1] = __builtin_nontemporal_load(ap + 1);
#pragma unroll
    for (int p = 0; p < 4; ++p)
      ps[p] = *reinterpret_cast<const bf16x8*>(sb + (size_t)(srow + p * 32) * N_DIM + kk + scol);
  };
  auto store_tile = [&](int buf) {
    bf16x8 v;
    v[0] = f2bf(pa[0].x); v[1] = f2bf(pa[0].y); v[2] = f2bf(pa[0].z); v[3] = f2bf(pa[0].w);
    v[4] = f2bf(pa[1].x); v[5] = f2bf(pa[1].y); v[6] = f2bf(pa[1].z); v[7] = f2bf(pa[1].w);
    *reinterpret_cast<bf16x8*>(&As[buf][arow * 72 + acol]) = v;
#pragma unroll
    for (int p = 0; p < 4; ++p)
      *reinterpret_cast<bf16x8*>(&Bs[buf][(srow + p * 32) * 72 + scol]) = ps[p];
  };

  f32x4 acc[2][2] = {};
  const int q8 = (lane >> 4) << 3;
  const int c = lane & 15;

  load_tile(0);
  store_tile(0);
  __syncthreads();

  for (int it = 1; it <= 32; ++it) {
    const int cur = (it - 1) & 1;
    const int nxt = it & 1;
    if (it < 32) load_tile(it * 64);   // global loads in flight over compute
#pragma unroll
    for (int k2 = 0; k2 < 2; ++k2) {
      const int kb = k2 * 32 + q8;
      bf16x8 af[2], bfr[2];
#pragma unroll
      for (int mt = 0; mt < 2; ++mt)
        af[mt] = *reinterpret_cast<const bf16x8*>(&As[cur][(mt * 16 + c) * 72 + kb]);
#pragma unroll
      for (int nt = 0; nt < 2; ++nt)
        bfr[nt] = *reinterpret_cast<const bf16x8*>(&Bs[cur][(nsub + nt * 16 + c) * 72 + kb]);
#pragma unroll
      for (int mt = 0; mt < 2; ++mt)
#pragma unroll
        for (int nt = 0; nt < 2; ++nt)
          acc[mt][nt] = __builtin_amdgcn_mfma_f32_16x16x32_bf16(af[mt], bfr[nt],
                                                                acc[mt][nt], 0, 0, 0);
    }
    if (it < 32) store_tile(nxt);
    __syncthreads();
  }

  const int q = lane >> 4;
  float bv[2];
#pragma unroll
  for (int nt = 0; nt < 2; ++nt) bv[nt] = bias[nsub + nt * 16 + c];
#pragma unroll
  for (int mt = 0; mt < 2; ++mt)
#pragma unroll
    for (int nt = 0; nt < 2; ++nt)
#pragma unroll
      for (int r = 0; r < 4; ++r) {
        int m = m0 + mt * 16 + q * 4 + r;
        int j = nsub + nt * 16 + c;
        __builtin_nontemporal_store(acc[mt][nt][r] + bv[nt],
                                    &out[((size_t)b * N_DIM + m) * F_DIM + j]);
      }
}

extern "C" void kernel_launch(void* const* d_in, const int* in_sizes, int n_in,
                              void* d_out, int out_size, void* d_ws, size_t ws_size,
                              hipStream_t stream) {
  const float* x    = (const float*)d_in[0];
  const float* adj  = (const float*)d_in[1];
  const float* W    = (const float*)d_in[2];
  const float* bias = (const float*)d_in[3];
  float* out = (float*)d_out;
  __bf16* supT = (__bf16*)d_ws;   // 8*128*2048*2 = 4 MB scratch

  gcn_xw<<<B_DIM * 32, 256, 0, stream>>>(x, W, supT);
  gcn_adj<<<B_DIM * 64, 256, 0, stream>>>(adj, supT, bias, out);
}